// Round 10
// baseline (378.970 us; speedup 1.0000x reference)
//
#include <hip/hip_runtime.h>
#include <hip/hip_fp16.h>

#define HH 128
#define WW 128
#define NPIX (HH*WW)
#define NB 8
#define NHEADS 6
#define HD 32
#define SCALE 0.17677669529663687f

typedef _Float16 h2 __attribute__((ext_vector_type(2)));
typedef __fp16 g2 __attribute__((ext_vector_type(2)));
typedef _Float16 f16x4 __attribute__((ext_vector_type(4)));
typedef _Float16 f16x8 __attribute__((ext_vector_type(8)));
typedef float f4 __attribute__((ext_vector_type(4)));

#define LDK 40    // na2d padded k-stride
union U4 { g2 p2[2]; f16x4 v4; };
union U8 { g2 p2[4]; f16x8 v8; };

// ---------------- prep: WT[z][n][k] fp16 from W[z][k][n] fp32 ----------------
__global__ __launch_bounds__(512) void prep_wt(
    const float* __restrict__ Wq, const float* __restrict__ Wk,
    const float* __restrict__ Wv, _Float16* __restrict__ wt)
{
    int idx = blockIdx.x * 512 + threadIdx.x;      // 3*36864 total
    int mat = idx / 36864, rem = idx % 36864;
    int k = rem / 192, n = rem % 192;              // coalesced read over n
    const float* W = mat == 0 ? Wq : (mat == 1 ? Wk : Wv);
    wt[(size_t)mat * 36864 + (size_t)n * 192 + k] = (_Float16)W[(size_t)k * 192 + n];
}

__global__ __launch_bounds__(512) void prep_wo(
    const float* __restrict__ Wo, _Float16* __restrict__ woT)
{
    int idx = blockIdx.x * 512 + threadIdx.x;      // 36864
    int k = idx / 192, n = idx % 192;
    woT[(size_t)n * 192 + k] = (_Float16)Wo[(size_t)k * 192 + n];
}

// ---------------- xpose: [b][192c][16384p] fp32 -> [b][p][192c] fp16 ----------------
// Streaming transpose, no LDS: per iter lanes are pixel-consecutive (coalesced 256B reads),
// each thread gathers 8 channels of its pixel and stores one 16B chunk. Block covers
// 64 pixels x all 192 channels in 6 iters -> full 128B output lines assembled block-locally.
__global__ __launch_bounds__(256) void xpose(
    const float* __restrict__ x, const float* __restrict__ ctx,
    _Float16* __restrict__ xT, _Float16* __restrict__ ctxT)
{
    int bid = blockIdx.x;                 // 4096: 2048 per matrix
    const float* src = (bid < 2048) ? x : ctx;
    _Float16* dst = (bid < 2048) ? xT : ctxT;
    int pg = bid & 2047;
    int b = pg >> 8;                      // 256 blocks per batch-image
    int p0 = (pg & 255) * 64;
    int t = threadIdx.x;
    int p = p0 + (t & 63);
    int ccg = t >> 6;                     // 4 waves = 4 chunk-groups per iter

    const float* sb = src + (size_t)b * 192 * NPIX + p;
    _Float16* db = dst + ((size_t)b * NPIX + p) * 192;

    #pragma unroll
    for (int j = 0; j < 6; j++) {
        int c0 = j * 32 + ccg * 8;
        float v[8];
        #pragma unroll
        for (int jj = 0; jj < 8; jj++) v[jj] = sb[(size_t)(c0 + jj) * NPIX];
        U8 u;
        u.p2[0] = __builtin_amdgcn_cvt_pkrtz(v[0], v[1]);
        u.p2[1] = __builtin_amdgcn_cvt_pkrtz(v[2], v[3]);
        u.p2[2] = __builtin_amdgcn_cvt_pkrtz(v[4], v[5]);
        u.p2[3] = __builtin_amdgcn_cvt_pkrtz(v[6], v[7]);
        *(f16x8*)&db[c0] = u.v8;
    }
}

// ---------------- MFMA projection v6: zero LDS, zero barriers ----------------
// Both operands fragment-shaped fp16 from global: WT (L2, hoisted to regs for all 6 k-steps)
// and xT/ctxT (L1-resident 48KB pixel tile). mfma(A=W rows=channels, B=pixels).
// 6144 blocks x 256 threads; per XCD: 256 q-blocks then 512 interleaved (k,v) pairs.
__global__ __launch_bounds__(256) void proj_mfma(
    const _Float16* __restrict__ xT, const _Float16* __restrict__ ctxT,
    const _Float16* __restrict__ wt,
    const float* __restrict__ bq, const float* __restrict__ bk, const float* __restrict__ bv,
    _Float16* __restrict__ qh, _Float16* __restrict__ kh, _Float16* __restrict__ vh)
{
    int bid = blockIdx.x;
    int xcd = bid & 7;
    int i = bid >> 3;                 // 0..767
    int z, xb;
    if (i < 256) { z = 0; xb = xcd * 256 + i; }
    else { int j = i - 256; z = 1 + (j & 1); xb = xcd * 256 + (j >> 1); }

    const _Float16* A  = (z == 0) ? xT : ctxT;
    const _Float16* WT = wt + (size_t)z * 36864;
    const float* bias = (z == 0) ? bq : (z == 1 ? bk : bv);
    _Float16* outp = (z == 0) ? qh : (z == 1 ? kh : vh);
    float scale = (z == 0) ? SCALE : 1.f;

    int t = threadIdx.x;
    int m0 = xb * 64;
    int b  = m0 / NPIX;
    int p0 = m0 % NPIX;

    int lane = t & 63;
    int wn   = t >> 6;        // wave owns 48 channels
    int lq = lane & 15;
    int lk = lane >> 4;

    // hoist all WT fragments for this wave's 48 channels (18 loads in flight)
    f16x8 wf[6][3];
    #pragma unroll
    for (int ks = 0; ks < 6; ks++)
        #pragma unroll
        for (int ni = 0; ni < 3; ni++)
            wf[ks][ni] = *(const f16x8*)&WT[(size_t)(wn * 48 + ni * 16 + lq) * 192 + ks * 32 + lk * 8];

    const _Float16* Abase = A + ((size_t)b * NPIX + p0) * 192;
    f4 acc[4][3] = {};
    #pragma unroll
    for (int ks = 0; ks < 6; ks++) {
        #pragma unroll
        for (int mi = 0; mi < 4; mi++) {
            f16x8 pfr = *(const f16x8*)&Abase[(size_t)(mi * 16 + lq) * 192 + ks * 32 + lk * 8];
            #pragma unroll
            for (int ni = 0; ni < 3; ni++)
                acc[mi][ni] = __builtin_amdgcn_mfma_f32_16x16x32_f16(wf[ks][ni], pfr, acc[mi][ni], 0, 0, 0);
        }
    }

    // epilogue: lane owns pixel (C col = lq) and 4 consecutive channels -> 8B stores
    #pragma unroll
    for (int mi = 0; mi < 4; mi++) {
        int p = p0 + mi * 16 + lq;
        #pragma unroll
        for (int ni = 0; ni < 3; ni++) {
            int n0 = wn * 48 + ni * 16 + lk * 4;
            int g = n0 >> 5, d0 = n0 & 31;
            f4 v = acc[mi][ni];
            U4 u;
            u.p2[0] = __builtin_amdgcn_cvt_pkrtz((v[0] + bias[n0]) * scale,     (v[1] + bias[n0 + 1]) * scale);
            u.p2[1] = __builtin_amdgcn_cvt_pkrtz((v[2] + bias[n0 + 2]) * scale, (v[3] + bias[n0 + 3]) * scale);
            *(f16x4*)(outp + ((size_t)(b * NHEADS + g) * NPIX + p) * HD + d0) = u.v4;
        }
    }
}

// ---------------- MFMA neighborhood attention (unchanged from R6-R9) ----------------
#define KS_ELE 33280            // 26*32*40 fp16
#define NA2D_SMEM 134912

template<int K>
__device__ __forceinline__ void na2d_tile(
    const _Float16* __restrict__ qh, const _Float16* __restrict__ kh,
    const _Float16* __restrict__ vh, const float* __restrict__ rpb,
    _Float16* __restrict__ ah, char* smem, int b, int g_head, int hi, int ty, int tx)
{
    constexpr int NS = K / 2;
    constexpr int RW = 2 * K - 1;
    _Float16* Ks = (_Float16*)smem;
    _Float16* Vt = Ks + KS_ELE;
    float* rpbs = (float*)(smem + 2 * KS_ELE * 2);

    int t = threadIdx.x;
    size_t plane = (size_t)(b * NHEADS + g_head) * NPIX;
    int h0 = ty * 16, w0 = tx * 16;
    int rmin = min(max(h0 - NS, 0), HH - K);
    int rtop = min(max(h0 + 15 - NS, 0), HH - K);
    int rows_n = rtop + K - rmin;
    int cwin0 = min(max(w0 - NS, 0), WW - K);
    int ctop = min(max(w0 + 15 - NS, 0), WW - K);
    int cols_n = ctop + K - cwin0;

    for (int i = t; i < RW * RW; i += 512) rpbs[i] = rpb[(size_t)hi * RW * RW + i];

    int ntask = rows_n * 128;
    for (int idx = t; idx < ntask; idx += 512) {
        int row = idx >> 7;
        int key = (idx >> 2) & 31;
        int dc  = idx & 3;
        f16x8 kv = {0,0,0,0,0,0,0,0};
        f16x8 vvv = {0,0,0,0,0,0,0,0};
        if (key < cols_n) {
            size_t pix = plane + (size_t)(rmin + row) * WW + (cwin0 + key);
            kv = *(const f16x8*)&kh[pix * HD + dc * 8];
            vvv = *(const f16x8*)&vh[pix * HD + dc * 8];
        }
        *(f16x8*)&Ks[row * 1280 + key * LDK + dc * 8] = kv;
        int m = 8 * ((key & 15) >> 2) + 4 * (key >> 4) + (key & 3);
        #pragma unroll
        for (int j = 0; j < 8; j++)
            Vt[row * 1280 + (dc * 8 + j) * LDK + m] = vvv[j];
    }
    __syncthreads();

    int lane = t & 63, wid = t >> 6;
    int lq = lane & 15, lg = lane >> 4;
    int wq = w0 + lq;
    int c0q = min(max(wq - NS, 0), WW - K);
    int klo = c0q - cwin0;
    int shiftc = cwin0 - wq + K - 1;
    f4 zf4 = {0.f, 0.f, 0.f, 0.f};

    #pragma unroll 1
    for (int qi = 0; qi < 2; qi++) {
        int qr = wid * 2 + qi;
        int h = h0 + qr;
        int r0q = min(max(h - NS, 0), HH - K);
        int row_base = r0q - rmin;
        f16x8 qf = *(const f16x8*)&qh[(plane + (size_t)h * WW + w0 + lq) * HD + lg * 8];
        f4 acc0 = zf4, acc1 = zf4;
        float lsum = 0.f;

        #pragma unroll 1
        for (int ki = 0; ki < K; ki++) {
            int row = row_base + ki;
            const _Float16* kbase = &Ks[row * 1280 + lg * 8];
            f16x8 a0 = *(const f16x8*)&kbase[lq * LDK];
            f16x8 a1 = *(const f16x8*)&kbase[(16 + lq) * LDK];
            f4 s0 = __builtin_amdgcn_mfma_f32_16x16x32_f16(a0, qf, zf4, 0, 0, 0);
            f4 s1 = __builtin_amdgcn_mfma_f32_16x16x32_f16(a1, qf, zf4, 0, 0, 0);

            int rel_r = r0q + ki - h + K - 1;
            const float* rrow = rpbs + rel_r * RW;
            float pf[2][4];
            #pragma unroll
            for (int c = 0; c < 2; c++) {
                #pragma unroll
                for (int r = 0; r < 4; r++) {
                    int key_local = c * 16 + 4 * lg + r;
                    int rc = key_local + shiftc;
                    rc = min(max(rc, 0), RW - 1);
                    float biasv = rrow[rc];
                    bool valid = (unsigned)(key_local - klo) < (unsigned)K;
                    float sv = (c ? s1[r] : s0[r]) + biasv;
                    float pv = valid ? __expf(sv) : 0.f;
                    pf[c][r] = pv;
                    lsum += pv;
                }
            }
            union { g2 p[4]; f16x8 v; } P;
            P.p[0] = __builtin_amdgcn_cvt_pkrtz(pf[0][0], pf[0][1]);
            P.p[1] = __builtin_amdgcn_cvt_pkrtz(pf[0][2], pf[0][3]);
            P.p[2] = __builtin_amdgcn_cvt_pkrtz(pf[1][0], pf[1][1]);
            P.p[3] = __builtin_amdgcn_cvt_pkrtz(pf[1][2], pf[1][3]);

            const _Float16* vbase = &Vt[row * 1280 + lg * 8];
            f16x8 b0 = *(const f16x8*)&vbase[lq * LDK];
            f16x8 b1 = *(const f16x8*)&vbase[(16 + lq) * LDK];
            acc0 = __builtin_amdgcn_mfma_f32_16x16x32_f16(P.v, b0, acc0, 0, 0, 0);
            acc1 = __builtin_amdgcn_mfma_f32_16x16x32_f16(P.v, b1, acc1, 0, 0, 0);
        }

        lsum += __shfl_xor(lsum, 16);
        lsum += __shfl_xor(lsum, 32);
        float inv = 1.f / lsum;
        _Float16* obase = ah + (plane + (size_t)h * WW + w0) * HD;
        #pragma unroll
        for (int r = 0; r < 4; r++) {
            float ir = __shfl(inv, 4 * lg + r);
            obase[(4 * lg + r) * HD + lq]      = (_Float16)(acc0[r] * ir);
            obase[(4 * lg + r) * HD + lq + 16] = (_Float16)(acc1[r] * ir);
        }
    }
}

__global__ __launch_bounds__(512) void na2d_mfma(
    const _Float16* __restrict__ qh, const _Float16* __restrict__ kh,
    const _Float16* __restrict__ vh,
    const float* __restrict__ rpb0, const float* __restrict__ rpb1,
    const float* __restrict__ rpb2, _Float16* __restrict__ ah)
{
    extern __shared__ char smem[];
    int bid = blockIdx.x;
    int xcd = bid & 7;
    int i = bid >> 3;
    int phase = i >> 7;
    int j = i & 127;
    int lb = xcd * 128 + j;
    int bz = lb >> 6;
    int tile = lb & 63;
    int b = bz >> 1, hi = bz & 1;
    int ty = tile >> 3, tx = tile & 7;
    if (phase == 0)      na2d_tile<7>(qh, kh, vh, rpb0, ah, smem, b, 0 + hi, hi, ty, tx);
    else if (phase == 1) na2d_tile<9>(qh, kh, vh, rpb1, ah, smem, b, 2 + hi, hi, ty, tx);
    else                 na2d_tile<11>(qh, kh, vh, rpb2, ah, smem, b, 4 + hi, hi, ty, tx);
}

// ---------------- MFMA output projection (unchanged from R9) ----------------
__global__ __launch_bounds__(512) void oproj_mfma(
    const _Float16* __restrict__ ah, const _Float16* __restrict__ woT,
    const float* __restrict__ bo, float* __restrict__ outp)
{
    int t = threadIdx.x;
    int m0 = blockIdx.x * 128;
    int b  = m0 / NPIX;
    int p0 = m0 % NPIX;

    int lane = t & 63;
    int wid  = t >> 6;
    int wm = wid & 1;
    int wn = wid >> 1;
    int lr = lane & 15;
    int lk = lane >> 4;

    f4 acc[4][3] = {};

    #pragma unroll
    for (int ks = 0; ks < 6; ks++) {
        const _Float16* abase = ah + (size_t)(b * NHEADS + ks) * NPIX * HD;
        f16x8 af[4], bf[3];
        #pragma unroll
        for (int mi = 0; mi < 4; mi++)
            af[mi] = *(const f16x8*)&abase[(size_t)(p0 + wm * 64 + mi * 16 + lr) * HD + lk * 8];
        #pragma unroll
        for (int ni = 0; ni < 3; ni++)
            bf[ni] = *(const f16x8*)&woT[(size_t)(wn * 48 + ni * 16 + lr) * 192 + ks * 32 + lk * 8];
        #pragma unroll
        for (int mi = 0; mi < 4; mi++)
            #pragma unroll
            for (int ni = 0; ni < 3; ni++)
                acc[mi][ni] = __builtin_amdgcn_mfma_f32_16x16x32_f16(af[mi], bf[ni], acc[mi][ni], 0, 0, 0);
    }

    #pragma unroll
    for (int ni = 0; ni < 3; ni++) {
        int n = wn * 48 + ni * 16 + lr;
        float bb = bo[n];
        float* obase = outp + ((size_t)b * 192 + n) * NPIX + p0 + wm * 64;
        #pragma unroll
        for (int mi = 0; mi < 4; mi++) {
            f4 v = acc[mi][ni];
            v[0] += bb; v[1] += bb; v[2] += bb; v[3] += bb;
            *(f4*)&obase[mi * 16 + lk * 4] = v;
        }
    }
}

extern "C" void kernel_launch(void* const* d_in, const int* in_sizes, int n_in,
                              void* d_out, int out_size, void* d_ws, size_t ws_size,
                              hipStream_t stream) {
    const float* x    = (const float*)d_in[0];
    const float* ctx  = (const float*)d_in[1];
    const float* Wq   = (const float*)d_in[2];
    const float* bq   = (const float*)d_in[3];
    const float* Wk   = (const float*)d_in[4];
    const float* bk   = (const float*)d_in[5];
    const float* Wv   = (const float*)d_in[6];
    const float* bv   = (const float*)d_in[7];
    const float* Wo   = (const float*)d_in[8];
    const float* bo   = (const float*)d_in[9];
    const float* rpb0 = (const float*)d_in[10];
    const float* rpb1 = (const float*)d_in[11];
    const float* rpb2 = (const float*)d_in[12];

    size_t N = (size_t)NB * NHEADS * NPIX * HD;   // 25,165,824 fp16 elements = 50.33MB
    _Float16* qh = (_Float16*)d_ws;
    _Float16* kh = qh + N;
    _Float16* vh = kh + N;
    _Float16* ah = vh + N;
    float* outp = (float*)d_out;

    // scratch parking (all dead by the time their region is overwritten):
    _Float16* xT   = (_Float16*)d_out;        // d_out = 100.66MB; xT uses first 50.33MB
    _Float16* wt   = (_Float16*)d_out + N;    // WT (221KB) in second half of d_out
    _Float16* ctxT = ah;                      // ah region free until na2d writes it
    _Float16* woT  = qh;                      // qh dead after na2d

    (void)hipFuncSetAttribute((const void*)na2d_mfma,
                              hipFuncAttributeMaxDynamicSharedMemorySize, NA2D_SMEM);

    prep_wt<<<216, 512, 0, stream>>>(Wq, Wk, Wv, wt);
    xpose<<<4096, 256, 0, stream>>>(x, ctx, xT, ctxT);
    proj_mfma<<<6144, 256, 0, stream>>>(xT, ctxT, wt, bq, bk, bv, qh, kh, vh);
    na2d_mfma<<<3072, 512, NA2D_SMEM, stream>>>(qh, kh, vh, rpb0, rpb1, rpb2, ah);
    prep_wo<<<72, 512, 0, stream>>>(Wo, woT);
    oproj_mfma<<<1024, 512, 0, stream>>>(ah, woT, bo, outp);
}

// Round 11
// 275.074 us; speedup vs baseline: 1.3777x; 1.3777x over previous
//
#include <hip/hip_runtime.h>
#include <hip/hip_fp16.h>

#define HH 128
#define WW 128
#define NPIX (HH*WW)
#define NB 8
#define NHEADS 6
#define HD 32
#define SCALE 0.17677669529663687f

typedef _Float16 h2 __attribute__((ext_vector_type(2)));
typedef __fp16 g2 __attribute__((ext_vector_type(2)));
typedef _Float16 f16x4 __attribute__((ext_vector_type(4)));
typedef _Float16 f16x8 __attribute__((ext_vector_type(8)));
typedef float f4 __attribute__((ext_vector_type(4)));

#define LDK 40    // na2d padded k-stride
union U4 { g2 p2[2]; f16x4 v4; };

// ---------------- prep: WT[z][n][k] fp16 from W[z][k][n] fp32 ----------------
__global__ __launch_bounds__(512) void prep_wt(
    const float* __restrict__ Wq, const float* __restrict__ Wk,
    const float* __restrict__ Wv, _Float16* __restrict__ wt)
{
    int idx = blockIdx.x * 512 + threadIdx.x;      // 3*36864 total
    int mat = idx / 36864, rem = idx % 36864;
    int k = rem / 192, n = rem % 192;              // coalesced read over n
    const float* W = mat == 0 ? Wq : (mat == 1 ? Wk : Wv);
    wt[(size_t)mat * 36864 + (size_t)n * 192 + k] = (_Float16)W[(size_t)k * 192 + n];
}

__global__ __launch_bounds__(512) void prep_wo(
    const float* __restrict__ Wo, _Float16* __restrict__ woT)
{
    int idx = blockIdx.x * 512 + threadIdx.x;      // 36864
    int k = idx / 192, n = idx % 192;
    woT[(size_t)n * 192 + k] = (_Float16)Wo[(size_t)k * 192 + n];
}

// ---------------- MFMA projection v7: one LDS tile, coalesced-everything ----------------
// A-tile staged once (fp32->fp16, XOR-swizzled flat [128][192], 48KB).
// WT fragments from global L2, hoisted per k-step (18 gathers/block total).
// Epilogue transposes through the SAME LDS tile so global stores are 16B/lane fully
// coalesced (wave = 1KB contiguous per head) instead of 36x 8B@64B-stride scatters.
__global__ __launch_bounds__(512, 2) void proj_mfma(
    const float* __restrict__ x, const float* __restrict__ ctx,
    const _Float16* __restrict__ wt,
    const float* __restrict__ bq, const float* __restrict__ bk, const float* __restrict__ bv,
    _Float16* __restrict__ qh, _Float16* __restrict__ kh, _Float16* __restrict__ vh)
{
    int bid = blockIdx.x;
    int xcd = bid & 7;
    int i = bid >> 3;                 // 0..383
    int z, xb;
    if (i < 128) { z = 0; xb = xcd * 128 + i; }
    else { int j = i - 128; z = 1 + (j & 1); xb = xcd * 128 + (j >> 1); }

    const float* A  = (z == 0) ? x : ctx;
    const _Float16* WT = wt + (size_t)z * 36864;
    const float* bias = (z == 0) ? bq : (z == 1 ? bk : bv);
    _Float16* outp = (z == 0) ? qh : (z == 1 ? kh : vh);
    float scale = (z == 0) ? SCALE : 1.f;

    __shared__ _Float16 Ts[128 * 192];   // 48KB, XOR-swizzled: idx = pix*192 + (off ^ ((pix&7)<<3))

    int t = threadIdx.x;
    int m0 = xb * 128;
    int b  = m0 / NPIX;
    int p0 = m0 % NPIX;
    const float* Ab = A + (size_t)b * 192 * NPIX + p0;

    int lane = t & 63;
    int wid  = t >> 6;
    int wm = wid & 1;         // 2 m-halves of 64 pixels
    int wn = wid >> 1;        // 4 n-quarters of 48 channels
    int lq = lane & 15;
    int lk = lane >> 4;

    // ---- stage A tile once: coalesced fp32 reads (256B/instr), swizzled 8B LDS writes ----
    {
        int cq = t >> 7, pp = t & 127;
        int sw = (pp & 7) << 3;
        #pragma unroll
        for (int j = 0; j < 12; j++) {
            int c0 = cq * 48 + j * 4;
            float a0 = Ab[(size_t)(c0)     * NPIX + pp];
            float a1 = Ab[(size_t)(c0 + 1) * NPIX + pp];
            float a2 = Ab[(size_t)(c0 + 2) * NPIX + pp];
            float a3 = Ab[(size_t)(c0 + 3) * NPIX + pp];
            U4 u;
            u.p2[0] = __builtin_amdgcn_cvt_pkrtz(a0, a1);
            u.p2[1] = __builtin_amdgcn_cvt_pkrtz(a2, a3);
            *(f16x4*)&Ts[pp * 192 + (c0 ^ sw)] = u.v4;
        }
    }
    __syncthreads();

    // ---- MFMA loop: WT frags hoisted per k-step, A frags from swizzled LDS ----
    f4 acc[12] = {};
    #pragma unroll
    for (int ks = 0; ks < 6; ks++) {
        f16x8 wf[3];
        #pragma unroll
        for (int ni = 0; ni < 3; ni++)
            wf[ni] = *(const f16x8*)&WT[(size_t)(wn * 48 + ni * 16 + lq) * 192 + ks * 32 + lk * 8];
        #pragma unroll
        for (int mi = 0; mi < 4; mi++) {
            int pix = wm * 64 + mi * 16 + lq;
            f16x8 pfr = *(const f16x8*)&Ts[pix * 192 + ((ks * 32 + lk * 8) ^ ((pix & 7) << 3))];
            #pragma unroll
            for (int ni = 0; ni < 3; ni++)
                acc[mi * 3 + ni] = __builtin_amdgcn_mfma_f32_16x16x32_f16(wf[ni], pfr, acc[mi * 3 + ni], 0, 0, 0);
        }
    }
    __syncthreads();   // done reading A; reuse Ts for output transpose

    // ---- transpose: lane owns pixel, 4 consecutive channels -> swizzled 8B LDS writes ----
    #pragma unroll
    for (int mi = 0; mi < 4; mi++) {
        int pix = wm * 64 + mi * 16 + lq;
        int sw = (pix & 7) << 3;
        #pragma unroll
        for (int ni = 0; ni < 3; ni++) {
            int n0 = wn * 48 + ni * 16 + lk * 4;
            f4 v = acc[mi * 3 + ni];
            f4 bb = *(const f4*)&bias[n0];
            U4 u;
            u.p2[0] = __builtin_amdgcn_cvt_pkrtz((v[0] + bb[0]) * scale, (v[1] + bb[1]) * scale);
            u.p2[1] = __builtin_amdgcn_cvt_pkrtz((v[2] + bb[2]) * scale, (v[3] + bb[3]) * scale);
            *(f16x4*)&Ts[pix * 192 + (n0 ^ sw)] = u.v4;
        }
    }
    __syncthreads();

    // ---- coalesced store: thread -> (pixel p2, 16B chunk qc); 6 heads x 16B ----
    {
        int p2 = t >> 2, qc = t & 3;
        int sw = (p2 & 7) << 3;
        #pragma unroll
        for (int g = 0; g < 6; g++) {
            f16x8 val = *(const f16x8*)&Ts[p2 * 192 + ((g * 32 + qc * 8) ^ sw)];
            *(f16x8*)(outp + ((size_t)(b * NHEADS + g) * NPIX + p0 + p2) * HD + qc * 8) = val;
        }
    }
}

// ---------------- MFMA neighborhood attention (unchanged from R6-R10) ----------------
#define KS_ELE 33280            // 26*32*40 fp16
#define NA2D_SMEM 134912

template<int K>
__device__ __forceinline__ void na2d_tile(
    const _Float16* __restrict__ qh, const _Float16* __restrict__ kh,
    const _Float16* __restrict__ vh, const float* __restrict__ rpb,
    _Float16* __restrict__ ah, char* smem, int b, int g_head, int hi, int ty, int tx)
{
    constexpr int NS = K / 2;
    constexpr int RW = 2 * K - 1;
    _Float16* Ks = (_Float16*)smem;
    _Float16* Vt = Ks + KS_ELE;
    float* rpbs = (float*)(smem + 2 * KS_ELE * 2);

    int t = threadIdx.x;
    size_t plane = (size_t)(b * NHEADS + g_head) * NPIX;
    int h0 = ty * 16, w0 = tx * 16;
    int rmin = min(max(h0 - NS, 0), HH - K);
    int rtop = min(max(h0 + 15 - NS, 0), HH - K);
    int rows_n = rtop + K - rmin;
    int cwin0 = min(max(w0 - NS, 0), WW - K);
    int ctop = min(max(w0 + 15 - NS, 0), WW - K);
    int cols_n = ctop + K - cwin0;

    for (int i = t; i < RW * RW; i += 512) rpbs[i] = rpb[(size_t)hi * RW * RW + i];

    int ntask = rows_n * 128;
    for (int idx = t; idx < ntask; idx += 512) {
        int row = idx >> 7;
        int key = (idx >> 2) & 31;
        int dc  = idx & 3;
        f16x8 kv = {0,0,0,0,0,0,0,0};
        f16x8 vvv = {0,0,0,0,0,0,0,0};
        if (key < cols_n) {
            size_t pix = plane + (size_t)(rmin + row) * WW + (cwin0 + key);
            kv = *(const f16x8*)&kh[pix * HD + dc * 8];
            vvv = *(const f16x8*)&vh[pix * HD + dc * 8];
        }
        *(f16x8*)&Ks[row * 1280 + key * LDK + dc * 8] = kv;
        int m = 8 * ((key & 15) >> 2) + 4 * (key >> 4) + (key & 3);
        #pragma unroll
        for (int j = 0; j < 8; j++)
            Vt[row * 1280 + (dc * 8 + j) * LDK + m] = vvv[j];
    }
    __syncthreads();

    int lane = t & 63, wid = t >> 6;
    int lq = lane & 15, lg = lane >> 4;
    int wq = w0 + lq;
    int c0q = min(max(wq - NS, 0), WW - K);
    int klo = c0q - cwin0;
    int shiftc = cwin0 - wq + K - 1;
    f4 zf4 = {0.f, 0.f, 0.f, 0.f};

    #pragma unroll 1
    for (int qi = 0; qi < 2; qi++) {
        int qr = wid * 2 + qi;
        int h = h0 + qr;
        int r0q = min(max(h - NS, 0), HH - K);
        int row_base = r0q - rmin;
        f16x8 qf = *(const f16x8*)&qh[(plane + (size_t)h * WW + w0 + lq) * HD + lg * 8];
        f4 acc0 = zf4, acc1 = zf4;
        float lsum = 0.f;

        #pragma unroll 1
        for (int ki = 0; ki < K; ki++) {
            int row = row_base + ki;
            const _Float16* kbase = &Ks[row * 1280 + lg * 8];
            f16x8 a0 = *(const f16x8*)&kbase[lq * LDK];
            f16x8 a1 = *(const f16x8*)&kbase[(16 + lq) * LDK];
            f4 s0 = __builtin_amdgcn_mfma_f32_16x16x32_f16(a0, qf, zf4, 0, 0, 0);
            f4 s1 = __builtin_amdgcn_mfma_f32_16x16x32_f16(a1, qf, zf4, 0, 0, 0);

            int rel_r = r0q + ki - h + K - 1;
            const float* rrow = rpbs + rel_r * RW;
            float pf[2][4];
            #pragma unroll
            for (int c = 0; c < 2; c++) {
                #pragma unroll
                for (int r = 0; r < 4; r++) {
                    int key_local = c * 16 + 4 * lg + r;
                    int rc = key_local + shiftc;
                    rc = min(max(rc, 0), RW - 1);
                    float biasv = rrow[rc];
                    bool valid = (unsigned)(key_local - klo) < (unsigned)K;
                    float sv = (c ? s1[r] : s0[r]) + biasv;
                    float pv = valid ? __expf(sv) : 0.f;
                    pf[c][r] = pv;
                    lsum += pv;
                }
            }
            union { g2 p[4]; f16x8 v; } P;
            P.p[0] = __builtin_amdgcn_cvt_pkrtz(pf[0][0], pf[0][1]);
            P.p[1] = __builtin_amdgcn_cvt_pkrtz(pf[0][2], pf[0][3]);
            P.p[2] = __builtin_amdgcn_cvt_pkrtz(pf[1][0], pf[1][1]);
            P.p[3] = __builtin_amdgcn_cvt_pkrtz(pf[1][2], pf[1][3]);

            const _Float16* vbase = &Vt[row * 1280 + lg * 8];
            f16x8 b0 = *(const f16x8*)&vbase[lq * LDK];
            f16x8 b1 = *(const f16x8*)&vbase[(16 + lq) * LDK];
            acc0 = __builtin_amdgcn_mfma_f32_16x16x32_f16(P.v, b0, acc0, 0, 0, 0);
            acc1 = __builtin_amdgcn_mfma_f32_16x16x32_f16(P.v, b1, acc1, 0, 0, 0);
        }

        lsum += __shfl_xor(lsum, 16);
        lsum += __shfl_xor(lsum, 32);
        float inv = 1.f / lsum;
        _Float16* obase = ah + (plane + (size_t)h * WW + w0) * HD;
        #pragma unroll
        for (int r = 0; r < 4; r++) {
            float ir = __shfl(inv, 4 * lg + r);
            obase[(4 * lg + r) * HD + lq]      = (_Float16)(acc0[r] * ir);
            obase[(4 * lg + r) * HD + lq + 16] = (_Float16)(acc1[r] * ir);
        }
    }
}

__global__ __launch_bounds__(512) void na2d_mfma(
    const _Float16* __restrict__ qh, const _Float16* __restrict__ kh,
    const _Float16* __restrict__ vh,
    const float* __restrict__ rpb0, const float* __restrict__ rpb1,
    const float* __restrict__ rpb2, _Float16* __restrict__ ah)
{
    extern __shared__ char smem[];
    int bid = blockIdx.x;
    int xcd = bid & 7;
    int i = bid >> 3;
    int phase = i >> 7;
    int j = i & 127;
    int lb = xcd * 128 + j;
    int bz = lb >> 6;
    int tile = lb & 63;
    int b = bz >> 1, hi = bz & 1;
    int ty = tile >> 3, tx = tile & 7;
    if (phase == 0)      na2d_tile<7>(qh, kh, vh, rpb0, ah, smem, b, 0 + hi, hi, ty, tx);
    else if (phase == 1) na2d_tile<9>(qh, kh, vh, rpb1, ah, smem, b, 2 + hi, hi, ty, tx);
    else                 na2d_tile<11>(qh, kh, vh, rpb2, ah, smem, b, 4 + hi, hi, ty, tx);
}

// ---------------- MFMA output projection (unchanged from R9/R10) ----------------
__global__ __launch_bounds__(512) void oproj_mfma(
    const _Float16* __restrict__ ah, const _Float16* __restrict__ woT,
    const float* __restrict__ bo, float* __restrict__ outp)
{
    int t = threadIdx.x;
    int m0 = blockIdx.x * 128;
    int b  = m0 / NPIX;
    int p0 = m0 % NPIX;

    int lane = t & 63;
    int wid  = t >> 6;
    int wm = wid & 1;
    int wn = wid >> 1;
    int lr = lane & 15;
    int lk = lane >> 4;

    f4 acc[4][3] = {};

    #pragma unroll
    for (int ks = 0; ks < 6; ks++) {
        const _Float16* abase = ah + (size_t)(b * NHEADS + ks) * NPIX * HD;
        f16x8 af[4], bf[3];
        #pragma unroll
        for (int mi = 0; mi < 4; mi++)
            af[mi] = *(const f16x8*)&abase[(size_t)(p0 + wm * 64 + mi * 16 + lr) * HD + lk * 8];
        #pragma unroll
        for (int ni = 0; ni < 3; ni++)
            bf[ni] = *(const f16x8*)&woT[(size_t)(wn * 48 + ni * 16 + lr) * 192 + ks * 32 + lk * 8];
        #pragma unroll
        for (int mi = 0; mi < 4; mi++)
            #pragma unroll
            for (int ni = 0; ni < 3; ni++)
                acc[mi][ni] = __builtin_amdgcn_mfma_f32_16x16x32_f16(af[mi], bf[ni], acc[mi][ni], 0, 0, 0);
    }

    #pragma unroll
    for (int ni = 0; ni < 3; ni++) {
        int n = wn * 48 + ni * 16 + lr;
        float bb = bo[n];
        float* obase = outp + ((size_t)b * 192 + n) * NPIX + p0 + wm * 64;
        #pragma unroll
        for (int mi = 0; mi < 4; mi++) {
            f4 v = acc[mi][ni];
            v[0] += bb; v[1] += bb; v[2] += bb; v[3] += bb;
            *(f4*)&obase[mi * 16 + lk * 4] = v;
        }
    }
}

extern "C" void kernel_launch(void* const* d_in, const int* in_sizes, int n_in,
                              void* d_out, int out_size, void* d_ws, size_t ws_size,
                              hipStream_t stream) {
    const float* x    = (const float*)d_in[0];
    const float* ctx  = (const float*)d_in[1];
    const float* Wq   = (const float*)d_in[2];
    const float* bq   = (const float*)d_in[3];
    const float* Wk   = (const float*)d_in[4];
    const float* bk   = (const float*)d_in[5];
    const float* Wv   = (const float*)d_in[6];
    const float* bv   = (const float*)d_in[7];
    const float* Wo   = (const float*)d_in[8];
    const float* bo   = (const float*)d_in[9];
    const float* rpb0 = (const float*)d_in[10];
    const float* rpb1 = (const float*)d_in[11];
    const float* rpb2 = (const float*)d_in[12];

    size_t N = (size_t)NB * NHEADS * NPIX * HD;   // 25,165,824 fp16 elements = 50.33MB
    _Float16* qh = (_Float16*)d_ws;
    _Float16* kh = qh + N;
    _Float16* vh = kh + N;
    _Float16* ah = vh + N;
    float* outp = (float*)d_out;

    // parking: WT fp16 in the second half of d_out (dead until oproj rewrites all of d_out);
    // woT in qh (dead after na2d).
    _Float16* wt  = (_Float16*)d_out + N;
    _Float16* woT = qh;

    (void)hipFuncSetAttribute((const void*)na2d_mfma,
                              hipFuncAttributeMaxDynamicSharedMemorySize, NA2D_SMEM);

    prep_wt<<<216, 512, 0, stream>>>(Wq, Wk, Wv, wt);
    proj_mfma<<<3072, 512, 0, stream>>>(x, ctx, wt, bq, bk, bv, qh, kh, vh);
    na2d_mfma<<<3072, 512, NA2D_SMEM, stream>>>(qh, kh, vh, rpb0, rpb1, rpb2, ah);
    prep_wo<<<72, 512, 0, stream>>>(Wo, woT);
    oproj_mfma<<<1024, 512, 0, stream>>>(ah, woT, bo, outp);
}

// Round 12
// 249.170 us; speedup vs baseline: 1.5209x; 1.1040x over previous
//
#include <hip/hip_runtime.h>
#include <hip/hip_fp16.h>

#define HH 128
#define WW 128
#define NPIX (HH*WW)
#define NB 8
#define NHEADS 6
#define HD 32
#define SCALE 0.17677669529663687f

typedef _Float16 h2 __attribute__((ext_vector_type(2)));
typedef __fp16 g2 __attribute__((ext_vector_type(2)));
typedef _Float16 f16x4 __attribute__((ext_vector_type(4)));
typedef _Float16 f16x8 __attribute__((ext_vector_type(8)));
typedef float f4 __attribute__((ext_vector_type(4)));

#define LDK 40    // na2d Vt padded stride (80B rows: 16B-aligned b128, 2-way banks = free)
union U4 { g2 p2[2]; f16x4 v4; };

// ---------------- prep: WT[z][n][k] fp16 from W[z][k][n] fp32 ----------------
__global__ __launch_bounds__(512) void prep_wt(
    const float* __restrict__ Wq, const float* __restrict__ Wk,
    const float* __restrict__ Wv, _Float16* __restrict__ wt)
{
    int idx = blockIdx.x * 512 + threadIdx.x;      // 3*36864 total
    int mat = idx / 36864, rem = idx % 36864;
    int k = rem / 192, n = rem % 192;              // coalesced read over n
    const float* W = mat == 0 ? Wq : (mat == 1 ? Wk : Wv);
    wt[(size_t)mat * 36864 + (size_t)n * 192 + k] = (_Float16)W[(size_t)k * 192 + n];
}

__global__ __launch_bounds__(512) void prep_wo(
    const float* __restrict__ Wo, _Float16* __restrict__ woT)
{
    int idx = blockIdx.x * 512 + threadIdx.x;      // 36864
    int k = idx / 192, n = idx % 192;
    woT[(size_t)n * 192 + k] = (_Float16)Wo[(size_t)k * 192 + n];
}

// ---------------- MFMA projection v7 (unchanged from R11) ----------------
__global__ __launch_bounds__(512, 2) void proj_mfma(
    const float* __restrict__ x, const float* __restrict__ ctx,
    const _Float16* __restrict__ wt,
    const float* __restrict__ bq, const float* __restrict__ bk, const float* __restrict__ bv,
    _Float16* __restrict__ qh, _Float16* __restrict__ kh, _Float16* __restrict__ vh)
{
    int bid = blockIdx.x;
    int xcd = bid & 7;
    int i = bid >> 3;                 // 0..383
    int z, xb;
    if (i < 128) { z = 0; xb = xcd * 128 + i; }
    else { int j = i - 128; z = 1 + (j & 1); xb = xcd * 128 + (j >> 1); }

    const float* A  = (z == 0) ? x : ctx;
    const _Float16* WT = wt + (size_t)z * 36864;
    const float* bias = (z == 0) ? bq : (z == 1 ? bk : bv);
    _Float16* outp = (z == 0) ? qh : (z == 1 ? kh : vh);
    float scale = (z == 0) ? SCALE : 1.f;

    __shared__ _Float16 Ts[128 * 192];   // 48KB, XOR-swizzled: idx = pix*192 + (off ^ ((pix&7)<<3))

    int t = threadIdx.x;
    int m0 = xb * 128;
    int b  = m0 / NPIX;
    int p0 = m0 % NPIX;
    const float* Ab = A + (size_t)b * 192 * NPIX + p0;

    int lane = t & 63;
    int wid  = t >> 6;
    int wm = wid & 1;
    int wn = wid >> 1;
    int lq = lane & 15;
    int lk = lane >> 4;

    {
        int cq = t >> 7, pp = t & 127;
        int sw = (pp & 7) << 3;
        #pragma unroll
        for (int j = 0; j < 12; j++) {
            int c0 = cq * 48 + j * 4;
            float a0 = Ab[(size_t)(c0)     * NPIX + pp];
            float a1 = Ab[(size_t)(c0 + 1) * NPIX + pp];
            float a2 = Ab[(size_t)(c0 + 2) * NPIX + pp];
            float a3 = Ab[(size_t)(c0 + 3) * NPIX + pp];
            U4 u;
            u.p2[0] = __builtin_amdgcn_cvt_pkrtz(a0, a1);
            u.p2[1] = __builtin_amdgcn_cvt_pkrtz(a2, a3);
            *(f16x4*)&Ts[pp * 192 + (c0 ^ sw)] = u.v4;
        }
    }
    __syncthreads();

    f4 acc[12] = {};
    #pragma unroll
    for (int ks = 0; ks < 6; ks++) {
        f16x8 wf[3];
        #pragma unroll
        for (int ni = 0; ni < 3; ni++)
            wf[ni] = *(const f16x8*)&WT[(size_t)(wn * 48 + ni * 16 + lq) * 192 + ks * 32 + lk * 8];
        #pragma unroll
        for (int mi = 0; mi < 4; mi++) {
            int pix = wm * 64 + mi * 16 + lq;
            f16x8 pfr = *(const f16x8*)&Ts[pix * 192 + ((ks * 32 + lk * 8) ^ ((pix & 7) << 3))];
            #pragma unroll
            for (int ni = 0; ni < 3; ni++)
                acc[mi * 3 + ni] = __builtin_amdgcn_mfma_f32_16x16x32_f16(wf[ni], pfr, acc[mi * 3 + ni], 0, 0, 0);
        }
    }
    __syncthreads();

    #pragma unroll
    for (int mi = 0; mi < 4; mi++) {
        int pix = wm * 64 + mi * 16 + lq;
        int sw = (pix & 7) << 3;
        #pragma unroll
        for (int ni = 0; ni < 3; ni++) {
            int n0 = wn * 48 + ni * 16 + lk * 4;
            f4 v = acc[mi * 3 + ni];
            f4 bb = *(const f4*)&bias[n0];
            U4 u;
            u.p2[0] = __builtin_amdgcn_cvt_pkrtz((v[0] + bb[0]) * scale, (v[1] + bb[1]) * scale);
            u.p2[1] = __builtin_amdgcn_cvt_pkrtz((v[2] + bb[2]) * scale, (v[3] + bb[3]) * scale);
            *(f16x4*)&Ts[pix * 192 + (n0 ^ sw)] = u.v4;
        }
    }
    __syncthreads();

    {
        int p2 = t >> 2, qc = t & 3;
        int sw = (p2 & 7) << 3;
        #pragma unroll
        for (int g = 0; g < 6; g++) {
            f16x8 val = *(const f16x8*)&Ts[p2 * 192 + ((g * 32 + qc * 8) ^ sw)];
            *(f16x8*)(outp + ((size_t)(b * NHEADS + g) * NPIX + p0 + p2) * HD + qc * 8) = val;
        }
    }
}

// ---------------- MFMA neighborhood attention v2: K direct from global/L2, V-only LDS ----------------
// LDS = Vt (26*32*40 fp16 = 66.5KB) + rpb table -> 68.3KB -> 2 blocks/CU (was 1 at 135KB).
// K A-fragments read from kh's natural layout: wave = 16 consecutive pixels x 32d = 1KB
// contiguous, L2-resident (4MB/XCD working set). Invalid key slots produce garbage scores
// that the existing valid-mask zeroes after exp (Inf/NaN-safe: select replaces, never adds).
#define NA2D_SMEM 68352          // 66560 (Vt) + 1764 (rpb) rounded

template<int K>
__device__ __forceinline__ void na2d_tile(
    const _Float16* __restrict__ qh, const _Float16* __restrict__ kh,
    const _Float16* __restrict__ vh, const float* __restrict__ rpb,
    _Float16* __restrict__ ah, char* smem, int b, int g_head, int hi, int ty, int tx)
{
    constexpr int NS = K / 2;
    constexpr int RW = 2 * K - 1;
    _Float16* Vt = (_Float16*)smem;
    float* rpbs = (float*)(smem + 66560);

    int t = threadIdx.x;
    size_t plane = (size_t)(b * NHEADS + g_head) * NPIX;
    int h0 = ty * 16, w0 = tx * 16;
    int rmin = min(max(h0 - NS, 0), HH - K);
    int rtop = min(max(h0 + 15 - NS, 0), HH - K);
    int rows_n = rtop + K - rmin;               // <= 26
    int cwin0 = min(max(w0 - NS, 0), WW - K);
    int ctop = min(max(w0 + 15 - NS, 0), WW - K);
    int cols_n = ctop + K - cwin0;              // <= 26

    for (int i = t; i < RW * RW; i += 512) rpbs[i] = rpb[(size_t)hi * RW * RW + i];

    // stage V only: [d][key-pi] transposed
    int ntask = rows_n * 128;                   // rows * 32 keys * 4 d-chunks
    for (int idx = t; idx < ntask; idx += 512) {
        int row = idx >> 7;
        int key = (idx >> 2) & 31;
        int dc  = idx & 3;
        f16x8 vvv = {0,0,0,0,0,0,0,0};
        if (key < cols_n) {
            size_t pix = plane + (size_t)(rmin + row) * WW + (cwin0 + key);
            vvv = *(const f16x8*)&vh[pix * HD + dc * 8];
        }
        int m = 8 * ((key & 15) >> 2) + 4 * (key >> 4) + (key & 3);   // pi^-1(key)
        #pragma unroll
        for (int j = 0; j < 8; j++)
            Vt[row * 1280 + (dc * 8 + j) * LDK + m] = vvv[j];
    }
    __syncthreads();

    int lane = t & 63, wid = t >> 6;
    int lq = lane & 15, lg = lane >> 4;
    int wq = w0 + lq;
    int c0q = min(max(wq - NS, 0), WW - K);
    int klo = c0q - cwin0;                       // valid key_local in [klo, klo+K)
    int shiftc = cwin0 - wq + K - 1;
    f4 zf4 = {0.f, 0.f, 0.f, 0.f};

    #pragma unroll 1
    for (int qi = 0; qi < 2; qi++) {
        int qr = wid * 2 + qi;
        int h = h0 + qr;
        int r0q = min(max(h - NS, 0), HH - K);
        int row_base = r0q - rmin;
        f16x8 qf = *(const f16x8*)&qh[(plane + (size_t)h * WW + w0 + lq) * HD + lg * 8];
        f4 acc0 = zf4, acc1 = zf4;
        float lsum = 0.f;

        #pragma unroll 1
        for (int ki = 0; ki < K; ki++) {
            int row = row_base + ki;
            // K fragments straight from global (L2): 1KB contiguous per 16-lane group
            const _Float16* kgrow = kh + (plane + (size_t)(rmin + row) * WW + cwin0) * HD;
            f16x8 a0 = *(const f16x8*)&kgrow[(size_t)lq * HD + lg * 8];
            f16x8 a1 = *(const f16x8*)&kgrow[(size_t)(16 + lq) * HD + lg * 8];
            f4 s0 = __builtin_amdgcn_mfma_f32_16x16x32_f16(a0, qf, zf4, 0, 0, 0);
            f4 s1 = __builtin_amdgcn_mfma_f32_16x16x32_f16(a1, qf, zf4, 0, 0, 0);

            int rel_r = r0q + ki - h + K - 1;            // uniform per (qr,ki)
            const float* rrow = rpbs + rel_r * RW;
            float pf[2][4];
            #pragma unroll
            for (int c = 0; c < 2; c++) {
                #pragma unroll
                for (int r = 0; r < 4; r++) {
                    int key_local = c * 16 + 4 * lg + r;
                    int rc = key_local + shiftc;
                    rc = min(max(rc, 0), RW - 1);
                    float biasv = rrow[rc];
                    bool valid = (unsigned)(key_local - klo) < (unsigned)K;
                    float sv = (c ? s1[r] : s0[r]) + biasv;
                    float pv = valid ? __expf(sv) : 0.f;
                    pf[c][r] = pv;
                    lsum += pv;
                }
            }
            union { g2 p[4]; f16x8 v; } P;
            P.p[0] = __builtin_amdgcn_cvt_pkrtz(pf[0][0], pf[0][1]);
            P.p[1] = __builtin_amdgcn_cvt_pkrtz(pf[0][2], pf[0][3]);
            P.p[2] = __builtin_amdgcn_cvt_pkrtz(pf[1][0], pf[1][1]);
            P.p[3] = __builtin_amdgcn_cvt_pkrtz(pf[1][2], pf[1][3]);

            const _Float16* vbase = &Vt[row * 1280 + lg * 8];
            f16x8 b0 = *(const f16x8*)&vbase[lq * LDK];
            f16x8 b1 = *(const f16x8*)&vbase[(16 + lq) * LDK];
            acc0 = __builtin_amdgcn_mfma_f32_16x16x32_f16(P.v, b0, acc0, 0, 0, 0);
            acc1 = __builtin_amdgcn_mfma_f32_16x16x32_f16(P.v, b1, acc1, 0, 0, 0);
        }

        lsum += __shfl_xor(lsum, 16);
        lsum += __shfl_xor(lsum, 32);
        float inv = 1.f / lsum;
        _Float16* obase = ah + (plane + (size_t)h * WW + w0) * HD;
        #pragma unroll
        for (int r = 0; r < 4; r++) {
            float ir = __shfl(inv, 4 * lg + r);
            obase[(4 * lg + r) * HD + lq]      = (_Float16)(acc0[r] * ir);
            obase[(4 * lg + r) * HD + lq + 16] = (_Float16)(acc1[r] * ir);
        }
    }
}

__global__ __launch_bounds__(512) void na2d_mfma(
    const _Float16* __restrict__ qh, const _Float16* __restrict__ kh,
    const _Float16* __restrict__ vh,
    const float* __restrict__ rpb0, const float* __restrict__ rpb1,
    const float* __restrict__ rpb2, _Float16* __restrict__ ah)
{
    extern __shared__ char smem[];
    int bid = blockIdx.x;
    int xcd = bid & 7;
    int i = bid >> 3;
    int phase = i >> 7;
    int j = i & 127;
    int lb = xcd * 128 + j;
    int bz = lb >> 6;
    int tile = lb & 63;
    int b = bz >> 1, hi = bz & 1;
    int ty = tile >> 3, tx = tile & 7;
    if (phase == 0)      na2d_tile<7>(qh, kh, vh, rpb0, ah, smem, b, 0 + hi, hi, ty, tx);
    else if (phase == 1) na2d_tile<9>(qh, kh, vh, rpb1, ah, smem, b, 2 + hi, hi, ty, tx);
    else                 na2d_tile<11>(qh, kh, vh, rpb2, ah, smem, b, 4 + hi, hi, ty, tx);
}

// ---------------- MFMA output projection (unchanged from R9-R11) ----------------
__global__ __launch_bounds__(512) void oproj_mfma(
    const _Float16* __restrict__ ah, const _Float16* __restrict__ woT,
    const float* __restrict__ bo, float* __restrict__ outp)
{
    int t = threadIdx.x;
    int m0 = blockIdx.x * 128;
    int b  = m0 / NPIX;
    int p0 = m0 % NPIX;

    int lane = t & 63;
    int wid  = t >> 6;
    int wm = wid & 1;
    int wn = wid >> 1;
    int lr = lane & 15;
    int lk = lane >> 4;

    f4 acc[4][3] = {};

    #pragma unroll
    for (int ks = 0; ks < 6; ks++) {
        const _Float16* abase = ah + (size_t)(b * NHEADS + ks) * NPIX * HD;
        f16x8 af[4], bf[3];
        #pragma unroll
        for (int mi = 0; mi < 4; mi++)
            af[mi] = *(const f16x8*)&abase[(size_t)(p0 + wm * 64 + mi * 16 + lr) * HD + lk * 8];
        #pragma unroll
        for (int ni = 0; ni < 3; ni++)
            bf[ni] = *(const f16x8*)&woT[(size_t)(wn * 48 + ni * 16 + lr) * 192 + ks * 32 + lk * 8];
        #pragma unroll
        for (int mi = 0; mi < 4; mi++)
            #pragma unroll
            for (int ni = 0; ni < 3; ni++)
                acc[mi][ni] = __builtin_amdgcn_mfma_f32_16x16x32_f16(af[mi], bf[ni], acc[mi][ni], 0, 0, 0);
    }

    #pragma unroll
    for (int ni = 0; ni < 3; ni++) {
        int n = wn * 48 + ni * 16 + lr;
        float bb = bo[n];
        float* obase = outp + ((size_t)b * 192 + n) * NPIX + p0 + wm * 64;
        #pragma unroll
        for (int mi = 0; mi < 4; mi++) {
            f4 v = acc[mi][ni];
            v[0] += bb; v[1] += bb; v[2] += bb; v[3] += bb;
            *(f4*)&obase[mi * 16 + lk * 4] = v;
        }
    }
}

extern "C" void kernel_launch(void* const* d_in, const int* in_sizes, int n_in,
                              void* d_out, int out_size, void* d_ws, size_t ws_size,
                              hipStream_t stream) {
    const float* x    = (const float*)d_in[0];
    const float* ctx  = (const float*)d_in[1];
    const float* Wq   = (const float*)d_in[2];
    const float* bq   = (const float*)d_in[3];
    const float* Wk   = (const float*)d_in[4];
    const float* bk   = (const float*)d_in[5];
    const float* Wv   = (const float*)d_in[6];
    const float* bv   = (const float*)d_in[7];
    const float* Wo   = (const float*)d_in[8];
    const float* bo   = (const float*)d_in[9];
    const float* rpb0 = (const float*)d_in[10];
    const float* rpb1 = (const float*)d_in[11];
    const float* rpb2 = (const float*)d_in[12];

    size_t N = (size_t)NB * NHEADS * NPIX * HD;   // 25,165,824 fp16 elements = 50.33MB
    _Float16* qh = (_Float16*)d_ws;
    _Float16* kh = qh + N;
    _Float16* vh = kh + N;
    _Float16* ah = vh + N;
    float* outp = (float*)d_out;

    // parking: WT fp16 in second half of d_out (dead until oproj); woT in qh (dead after na2d)
    _Float16* wt  = (_Float16*)d_out + N;
    _Float16* woT = qh;

    (void)hipFuncSetAttribute((const void*)na2d_mfma,
                              hipFuncAttributeMaxDynamicSharedMemorySize, NA2D_SMEM);

    prep_wt<<<216, 512, 0, stream>>>(Wq, Wk, Wv, wt);
    proj_mfma<<<3072, 512, 0, stream>>>(x, ctx, wt, bq, bk, bv, qh, kh, vh);
    na2d_mfma<<<3072, 512, NA2D_SMEM, stream>>>(qh, kh, vh, rpb0, rpb1, rpb2, ah);
    prep_wo<<<72, 512, 0, stream>>>(Wo, woT);
    oproj_mfma<<<1024, 512, 0, stream>>>(ah, woT, bo, outp);
}